// Round 4
// baseline (205.363 us; speedup 1.0000x reference)
//
#include <hip/hip_runtime.h>

#define BB 16384
#define NN 20
#define DD 64
#define IMGK 2048

using bf16x8 = __attribute__((ext_vector_type(8))) short;
using f32x4  = __attribute__((ext_vector_type(4))) float;

__device__ __forceinline__ float waveReduceSum(float x) {
#pragma unroll
  for (int off = 32; off > 0; off >>= 1) x += __shfl_xor(x, off, 64);
  return x;
}

__device__ __forceinline__ float fast_tanh(float x) {
  float e = __expf(2.f * x);
  return 1.f - __fdividef(2.f, e + 1.f);
}

__device__ __forceinline__ short f2bf(float f) {
  union { float f; unsigned u; } c; c.f = f;
  unsigned r = c.u + 0x7fffu + ((c.u >> 16) & 1u);
  return (short)(r >> 16);
}
__device__ __forceinline__ float bf2f(short s) {
  union { unsigned u; float f; } c; c.u = ((unsigned)(unsigned short)s) << 16;
  return c.f;
}

__device__ __forceinline__ unsigned cvt_pk_bf16(float lo, float hi) {
  unsigned r;
  asm("v_cvt_pk_bf16_f32 %0, %1, %2" : "=v"(r) : "v"(lo), "v"(hi));
  return r;
}

__device__ __forceinline__ bf16x8 pack8(float4 a, float4 b) {
  union { unsigned u[4]; bf16x8 v; } r;
  r.u[0] = cvt_pk_bf16(a.x, a.y);
  r.u[1] = cvt_pk_bf16(a.z, a.w);
  r.u[2] = cvt_pk_bf16(b.x, b.y);
  r.u[3] = cvt_pk_bf16(b.z, b.w);
  return r.v;
}

// ---------------- prep: transpose + split weights to bf16 ----------------
__global__ __launch_bounds__(256)
void prep_kernel(const float* __restrict__ Wimg, const float* __restrict__ W1,
                 short* __restrict__ Wt_hi, short* __restrict__ Wt_lo,
                 short* __restrict__ W1t) {
  int i = blockIdx.x * 256 + threadIdx.x;
  if (i < IMGK * 64) {
    int k = i >> 6, n = i & 63;
    float f = Wimg[i];
    short h = f2bf(f);
    Wt_hi[n * IMGK + k] = h;
    Wt_lo[n * IMGK + k] = f2bf(f - bf2f(h));
  } else if (i < IMGK * 64 + 64 * 64) {
    int j = i - IMGK * 64;
    int k = j >> 6, n = j & 63;
    W1t[n * 64 + k] = f2bf(W1[j]);
  }
}

// ---------------- Kernel A: img GEMM, 16-row blocks, 4-way K-split ----------------
// grid 1024, each wave K=512 (16 k-steps of 32), LDS partial combine.
__global__ __launch_bounds__(256, 4)
void img_gemm_mfma(const float* __restrict__ img_in,
                   const short* __restrict__ Wt_hi,
                   const short* __restrict__ Wt_lo,
                   const float* __restrict__ Wb,
                   const float* __restrict__ bimg,
                   float* __restrict__ img_out) {
  __shared__ float part[4][16][64];
  const int t = threadIdx.x;
  const int wave = t >> 6, lane = t & 63;
  const int r0 = blockIdx.x * 16;
  const int lr = lane & 15, lk = lane >> 4;
  const int kb = wave * 512;
  f32x4 aHH[4], aX1[4], aX2[4];
#pragma unroll
  for (int tt = 0; tt < 4; ++tt) {
    aHH[tt] = (f32x4){0.f, 0.f, 0.f, 0.f};
    aX1[tt] = (f32x4){0.f, 0.f, 0.f, 0.f};
    aX2[tt] = (f32x4){0.f, 0.f, 0.f, 0.f};
  }
  const float* arow = img_in + (size_t)(r0 + lr) * IMGK + kb + lk * 8;
  const short* wh0 = Wt_hi + (size_t)lr * IMGK + kb + lk * 8;
  const short* wl0 = Wt_lo + (size_t)lr * IMGK + kb + lk * 8;
#pragma unroll 4
  for (int ks = 0; ks < 16; ++ks) {
    const float4* ap = reinterpret_cast<const float4*>(arow + ks * 32);
    float4 va = ap[0], vb = ap[1];
    union { unsigned u[4]; bf16x8 v; } hi;
    hi.u[0] = cvt_pk_bf16(va.x, va.y);
    hi.u[1] = cvt_pk_bf16(va.z, va.w);
    hi.u[2] = cvt_pk_bf16(vb.x, vb.y);
    hi.u[3] = cvt_pk_bf16(vb.z, vb.w);
    float4 ra, rb;
    ra.x = va.x - __uint_as_float(hi.u[0] << 16);
    ra.y = va.y - __uint_as_float(hi.u[0] & 0xffff0000u);
    ra.z = va.z - __uint_as_float(hi.u[1] << 16);
    ra.w = va.w - __uint_as_float(hi.u[1] & 0xffff0000u);
    rb.x = vb.x - __uint_as_float(hi.u[2] << 16);
    rb.y = vb.y - __uint_as_float(hi.u[2] & 0xffff0000u);
    rb.z = vb.z - __uint_as_float(hi.u[3] << 16);
    rb.w = vb.w - __uint_as_float(hi.u[3] & 0xffff0000u);
    bf16x8 alo = pack8(ra, rb);
#pragma unroll
    for (int tt = 0; tt < 4; ++tt) {
      bf16x8 wh = *reinterpret_cast<const bf16x8*>(wh0 + (size_t)tt * 16 * IMGK + ks * 32);
      bf16x8 wl = *reinterpret_cast<const bf16x8*>(wl0 + (size_t)tt * 16 * IMGK + ks * 32);
      aHH[tt] = __builtin_amdgcn_mfma_f32_16x16x32_bf16(hi.v, wh, aHH[tt], 0, 0, 0);
      aX1[tt] = __builtin_amdgcn_mfma_f32_16x16x32_bf16(hi.v, wl, aX1[tt], 0, 0, 0);
      aX2[tt] = __builtin_amdgcn_mfma_f32_16x16x32_bf16(alo, wh, aX2[tt], 0, 0, 0);
    }
  }
#pragma unroll
  for (int tt = 0; tt < 4; ++tt)
#pragma unroll
    for (int r = 0; r < 4; ++r)
      part[wave][4 * lk + r][16 * tt + lr] = aHH[tt][r] + aX1[tt][r] + aX2[tt][r];
  __syncthreads();
  const int row = t >> 4, col = (t & 15) * 4;
  float4 s0 = *reinterpret_cast<const float4*>(&part[0][row][col]);
  float4 s1 = *reinterpret_cast<const float4*>(&part[1][row][col]);
  float4 s2 = *reinterpret_cast<const float4*>(&part[2][row][col]);
  float4 s3 = *reinterpret_cast<const float4*>(&part[3][row][col]);
  float4 wb = *reinterpret_cast<const float4*>(&Wb[col]);
  float4 bi = *reinterpret_cast<const float4*>(&bimg[col]);
  float4 o;
  o.x = s0.x + s1.x + s2.x + s3.x + wb.x + bi.x;
  o.y = s0.y + s1.y + s2.y + s3.y + wb.y + bi.y;
  o.z = s0.z + s1.z + s2.z + s3.z + wb.z + bi.z;
  o.w = s0.w + s1.w + s2.w + s3.w + wb.w + bi.w;
  *reinterpret_cast<float4*>(&img_out[(size_t)(r0 + row) * 64 + col]) = o;
}

// ---------------- Kernel A2: base[b][w] = [ue|img] @ Wi[64:192] + Wib + bai ----------------
__global__ __launch_bounds__(256, 4)
void base_kernel(const int* __restrict__ user_input,
                 const float* __restrict__ user_emb,
                 const float* __restrict__ ws_img,
                 const float* __restrict__ Wi,    // [192][64]
                 const float* __restrict__ Wib,   // [64]
                 const float* __restrict__ bai,   // [64]
                 float* __restrict__ ws_base) {
  __shared__ float W_s[128 * 64];
  __shared__ float x_s[4][128];
  const int t = threadIdx.x;
  for (int i = t; i < 128 * 64 / 4; i += 256)
    reinterpret_cast<float4*>(W_s)[i] =
        reinterpret_cast<const float4*>(Wi + 64 * 64)[i];
  __syncthreads();
  const int wave = t >> 6, lane = t & 63;
  const float bb = Wib[lane] + bai[lane];
  const int b0 = blockIdx.x * 32 + wave * 8;
#pragma unroll 1
  for (int bi = 0; bi < 8; ++bi) {
    const int b = b0 + bi;
    const int u = user_input[b];
    x_s[wave][lane] = user_emb[(size_t)u * 64 + lane];
    x_s[wave][64 + lane] = ws_img[(size_t)b * 64 + lane];
    asm volatile("s_waitcnt lgkmcnt(0)" ::: "memory");
    float acc = bb;
    const float4* x4 = reinterpret_cast<const float4*>(&x_s[wave][0]);
#pragma unroll
    for (int d0 = 0; d0 < 32; ++d0) {
      float4 q = x4[d0];
      int d = d0 * 4;
      acc = fmaf(q.x, W_s[(d + 0) * 64 + lane],
            fmaf(q.y, W_s[(d + 1) * 64 + lane],
            fmaf(q.z, W_s[(d + 2) * 64 + lane],
            fmaf(q.w, W_s[(d + 3) * 64 + lane], acc))));
    }
    ws_base[(size_t)b * 64 + lane] = acc;
    asm volatile("s_waitcnt lgkmcnt(0)" ::: "memory");
  }
}

// ---------------- Kernel B1: ingredient attention via MFMA ----------------
__global__ __launch_bounds__(256, 2)
void ingre_att_mfma(const int* __restrict__ ingre_input,
                    const int* __restrict__ ingre_num,
                    const float* __restrict__ ingre_emb,
                    const short* __restrict__ W1t,   // [64][64] bf16
                    const float* __restrict__ v,
                    const float* __restrict__ ws_base,
                    float* __restrict__ ws_ia) {
  __shared__ float sc_lds[4][32];
  const int t = threadIdx.x, wave = t >> 6, lane = t & 63;
  const int lr = lane & 15, lk = lane >> 4;
  bf16x8 wf[4][2];
#pragma unroll
  for (int wt = 0; wt < 4; ++wt)
#pragma unroll
    for (int ks = 0; ks < 2; ++ks)
      wf[wt][ks] = *reinterpret_cast<const bf16x8*>(
          W1t + (16 * wt + lr) * 64 + ks * 32 + lk * 8);
  float vv[4];
#pragma unroll
  for (int wt = 0; wt < 4; ++wt) vv[wt] = v[16 * wt + lr];
  const int b0 = blockIdx.x * 32 + wave * 8;
#pragma unroll 1
  for (int bi = 0; bi < 8; ++bi) {
    const int b = b0 + bi;
    const int n1 = 16 + lr;
    const int gi0 = ingre_input[b * NN + lr];
    const int gi1 = ingre_input[b * NN + ((n1 < NN) ? n1 : 0)];
    bf16x8 a0[2], a1[2];
#pragma unroll
    for (int ks = 0; ks < 2; ++ks) {
      const float4* p0 = reinterpret_cast<const float4*>(
          ingre_emb + (size_t)gi0 * 64 + ks * 32 + lk * 8);
      a0[ks] = pack8(p0[0], p0[1]);
      const float4* p1 = reinterpret_cast<const float4*>(
          ingre_emb + (size_t)gi1 * 64 + ks * 32 + lk * 8);
      a1[ks] = pack8(p1[0], p1[1]);
    }
    f32x4 acc[2][4];
#pragma unroll
    for (int nt = 0; nt < 2; ++nt)
#pragma unroll
      for (int wt = 0; wt < 4; ++wt) acc[nt][wt] = (f32x4){0.f, 0.f, 0.f, 0.f};
#pragma unroll
    for (int ks = 0; ks < 2; ++ks)
#pragma unroll
      for (int wt = 0; wt < 4; ++wt) {
        acc[0][wt] = __builtin_amdgcn_mfma_f32_16x16x32_bf16(a0[ks], wf[wt][ks], acc[0][wt], 0, 0, 0);
        acc[1][wt] = __builtin_amdgcn_mfma_f32_16x16x32_bf16(a1[ks], wf[wt][ks], acc[1][wt], 0, 0, 0);
      }
    float basew[4];
#pragma unroll
    for (int wt = 0; wt < 4; ++wt) basew[wt] = ws_base[(size_t)b * 64 + 16 * wt + lr];
    float sp[2][4];
#pragma unroll
    for (int nt = 0; nt < 2; ++nt)
#pragma unroll
      for (int r = 0; r < 4; ++r) {
        float s = 0.f;
#pragma unroll
        for (int wt = 0; wt < 4; ++wt) {
          float x = acc[nt][wt][r] + basew[wt];
          s = fmaf(fast_tanh(x), vv[wt], s);
        }
        sp[nt][r] = s;
      }
#pragma unroll
    for (int off = 1; off < 16; off <<= 1)
#pragma unroll
      for (int nt = 0; nt < 2; ++nt)
#pragma unroll
        for (int r = 0; r < 4; ++r) sp[nt][r] += __shfl_xor(sp[nt][r], off, 64);
    if (lr == 0) {
#pragma unroll
      for (int r = 0; r < 4; ++r) {
        sc_lds[wave][4 * lk + r] = sp[0][r];
        sc_lds[wave][16 + 4 * lk + r] = sp[1][r];
      }
    }
    asm volatile("s_waitcnt lgkmcnt(0)" ::: "memory");
    float scn[NN];
#pragma unroll
    for (int q = 0; q < 5; ++q) {
      float4 s4 = *reinterpret_cast<const float4*>(&sc_lds[wave][4 * q]);
      scn[4 * q + 0] = s4.x; scn[4 * q + 1] = s4.y;
      scn[4 * q + 2] = s4.z; scn[4 * q + 3] = s4.w;
    }
    asm volatile("s_waitcnt lgkmcnt(0)" ::: "memory");
    const int num = ingre_num[b];
    float m = -3e38f;
#pragma unroll
    for (int n = 0; n < NN; ++n) {
      scn[n] = (n < num) ? scn[n] : -1e12f;
      m = fmaxf(m, scn[n]);
    }
    float ev[NN], ssum = 0.f;
#pragma unroll
    for (int n = 0; n < NN; ++n) {
      ev[n] = __expf(scn[n] - m);
      ssum += ev[n];
    }
    const float inv = __fdividef(1.f, ssum);
    float qv[NN];
#pragma unroll
    for (int n = 0; n < NN; ++n) {
      const int gi = ingre_input[b * NN + n];
      qv[n] = ingre_emb[(size_t)gi * 64 + lane];
    }
    float ia = 0.f;
#pragma unroll
    for (int n = 0; n < NN; ++n) ia = fmaf(ev[n], qv[n], ia);
    ws_ia[(size_t)b * 64 + lane] = ia * inv;
  }
}

// ---------------- Kernel B2: component scores -> flat [3B] ----------------
__global__ __launch_bounds__(256, 4)
void com_score_kernel(const int* __restrict__ user_input,
                      const int* __restrict__ item_input,
                      const float* __restrict__ user_emb,
                      const float* __restrict__ item_emb,
                      const float* __restrict__ Wc,    // [128][64]
                      const float* __restrict__ Wcb,   // [64]
                      const float* __restrict__ bat,   // [64]
                      const float* __restrict__ vc,    // [64]
                      const float* __restrict__ ws_img,
                      const float* __restrict__ ws_ia,
                      float* __restrict__ ws_flat) {
  __shared__ float Wclds[128 * 64];
  __shared__ float x_s[4][4][64];
  const int t = threadIdx.x;
  for (int i = t; i < 128 * 64 / 4; i += 256)
    reinterpret_cast<float4*>(Wclds)[i] = reinterpret_cast<const float4*>(Wc)[i];
  __syncthreads();
  const int wave = t >> 6, lane = t & 63;
  const float bb = Wcb[lane] + bat[lane];
  const float vcl = vc[lane];
  const int b0 = blockIdx.x * 32 + wave * 8;
#pragma unroll 1
  for (int bi = 0; bi < 8; ++bi) {
    const int b = b0 + bi;
    const int u = user_input[b];
    const int it = item_input[b];
    x_s[wave][0][lane] = user_emb[(size_t)u * 64 + lane];
    x_s[wave][1][lane] = item_emb[(size_t)it * 64 + lane];
    x_s[wave][2][lane] = ws_ia[(size_t)b * 64 + lane];
    x_s[wave][3][lane] = ws_img[(size_t)b * 64 + lane];
    asm volatile("s_waitcnt lgkmcnt(0)" ::: "memory");
    const float4* u4 = reinterpret_cast<const float4*>(&x_s[wave][0][0]);
    float up = 0.f;
#pragma unroll
    for (int d0 = 0; d0 < 16; ++d0) {
      float4 q = u4[d0];
      int d = d0 * 4;
      up = fmaf(q.x, Wclds[(d + 0) * 64 + lane],
           fmaf(q.y, Wclds[(d + 1) * 64 + lane],
           fmaf(q.z, Wclds[(d + 2) * 64 + lane],
           fmaf(q.w, Wclds[(d + 3) * 64 + lane], up))));
    }
    float sc[3];
#pragma unroll
    for (int c = 0; c < 3; ++c) {
      const float4* y4 = reinterpret_cast<const float4*>(&x_s[wave][1 + c][0]);
      float s = bb + up;
#pragma unroll
      for (int d0 = 0; d0 < 16; ++d0) {
        float4 q = y4[d0];
        int d = 64 + d0 * 4;
        s = fmaf(q.x, Wclds[(d + 0) * 64 + lane],
            fmaf(q.y, Wclds[(d + 1) * 64 + lane],
            fmaf(q.z, Wclds[(d + 2) * 64 + lane],
            fmaf(q.w, Wclds[(d + 3) * 64 + lane], s))));
      }
      sc[c] = waveReduceSum(fast_tanh(s) * vcl);
    }
    if (lane == 0) {
      ws_flat[b] = sc[0];
      ws_flat[BB + b] = sc[1];
      ws_flat[2 * BB + b] = sc[2];
    }
    asm volatile("s_waitcnt lgkmcnt(0)" ::: "memory");
  }
}

// ---------------- Kernel C: head. scores[i][j] = flat[3i+j] ----------------
__global__ __launch_bounds__(256, 3)
void head_kernel(const int* __restrict__ user_input,
                 const int* __restrict__ item_input,
                 const float* __restrict__ user_emb,
                 const float* __restrict__ item_emb,
                 const float* __restrict__ Wcat,   // [192][64]
                 const float* __restrict__ Wcatb,  // [64]
                 const float* __restrict__ bcat,   // [64]
                 const float* __restrict__ hw,     // [64]
                 const float* __restrict__ hb,     // [1]
                 const float* __restrict__ ws_img,
                 const float* __restrict__ ws_ia,
                 const float* __restrict__ ws_flat,
                 float* __restrict__ out) {
  __shared__ float Wlds[192 * 64];
  __shared__ float ue_s[4][64];
  __shared__ float itt_s[4][64];
  const int t = threadIdx.x;
  for (int i = t; i < 192 * 64 / 4; i += 256)
    reinterpret_cast<float4*>(Wlds)[i] = reinterpret_cast<const float4*>(Wcat)[i];
  __syncthreads();
  const int wave = t >> 6, lane = t & 63;
  const float bb = Wcatb[lane] + bcat[lane];
  const float hwl = hw[lane];
  const float hbv = hb[0];
  const int b0 = blockIdx.x * 32 + wave * 8;
#pragma unroll 1
  for (int bi = 0; bi < 8; ++bi) {
    const int b = b0 + bi;
    const float s0 = ws_flat[3 * b + 0];
    const float s1 = ws_flat[3 * b + 1];
    const float s2 = ws_flat[3 * b + 2];
    const float m = fmaxf(s0, fmaxf(s1, s2));
    const float e0 = __expf(s0 - m), e1 = __expf(s1 - m), e2 = __expf(s2 - m);
    const float inv = 1.0f / (e0 + e1 + e2);
    const int u = user_input[b];
    const int it = item_input[b];
    const float uev = user_emb[(size_t)u * 64 + lane];
    const float itt = (e0 * item_emb[(size_t)it * 64 + lane] +
                       e1 * ws_ia[(size_t)b * 64 + lane] +
                       e2 * ws_img[(size_t)b * 64 + lane]) * inv;
    ue_s[wave][lane] = uev;
    itt_s[wave][lane] = itt;
    asm volatile("s_waitcnt lgkmcnt(0)" ::: "memory");
    const float4* u4 = reinterpret_cast<const float4*>(&ue_s[wave][0]);
    const float4* i4 = reinterpret_cast<const float4*>(&itt_s[wave][0]);
    float h = bb;
#pragma unroll
    for (int d0 = 0; d0 < 16; ++d0) {
      float4 uu = u4[d0];
      float4 ii = i4[d0];
      int d = d0 * 4;
      h = fmaf(uu.x, Wlds[(d + 0) * 64 + lane], h);
      h = fmaf(ii.x, Wlds[(64 + d + 0) * 64 + lane], h);
      h = fmaf(uu.x * ii.x, Wlds[(128 + d + 0) * 64 + lane], h);
      h = fmaf(uu.y, Wlds[(d + 1) * 64 + lane], h);
      h = fmaf(ii.y, Wlds[(64 + d + 1) * 64 + lane], h);
      h = fmaf(uu.y * ii.y, Wlds[(128 + d + 1) * 64 + lane], h);
      h = fmaf(uu.z, Wlds[(d + 2) * 64 + lane], h);
      h = fmaf(ii.z, Wlds[(64 + d + 2) * 64 + lane], h);
      h = fmaf(uu.z * ii.z, Wlds[(128 + d + 2) * 64 + lane], h);
      h = fmaf(uu.w, Wlds[(d + 3) * 64 + lane], h);
      h = fmaf(ii.w, Wlds[(64 + d + 3) * 64 + lane], h);
      h = fmaf(uu.w * ii.w, Wlds[(128 + d + 3) * 64 + lane], h);
    }
    h = fmaxf(h, 0.f) * hwl;
    float o = waveReduceSum(h);
    if (lane == 0) out[b] = o + hbv;
    asm volatile("s_waitcnt lgkmcnt(0)" ::: "memory");
  }
}

extern "C" void kernel_launch(void* const* d_in, const int* in_sizes, int n_in,
                              void* d_out, int out_size, void* d_ws, size_t ws_size,
                              hipStream_t stream) {
  (void)in_sizes; (void)n_in; (void)out_size; (void)ws_size;
  const int* user_input = (const int*)d_in[0];
  const int* item_input = (const int*)d_in[1];
  const int* ingre_input = (const int*)d_in[2];
  const float* image_input = (const float*)d_in[3];
  const int* ingre_num = (const int*)d_in[4];
  const float* user_emb = (const float*)d_in[5];
  const float* item_emb = (const float*)d_in[6];
  const float* ingre_emb = (const float*)d_in[7];
  const float* W_image_w = (const float*)d_in[8];
  const float* W_image_b = (const float*)d_in[9];
  const float* b_image = (const float*)d_in[10];
  const float* W_concat_w = (const float*)d_in[11];
  const float* W_concat_b = (const float*)d_in[12];
  const float* b_concat = (const float*)d_in[13];
  const float* h_w = (const float*)d_in[14];
  const float* h_b = (const float*)d_in[15];
  const float* W_att_ingre_w = (const float*)d_in[16];
  const float* W_att_ingre_b = (const float*)d_in[17];
  const float* b_att_ingre = (const float*)d_in[18];
  const float* v = (const float*)d_in[19];
  const float* W_att_com_w = (const float*)d_in[20];
  const float* W_att_com_b = (const float*)d_in[21];
  const float* b_att_com = (const float*)d_in[22];
  const float* v_c = (const float*)d_in[23];

  float* ws = (float*)d_ws;
  float* ws_img = ws;                              // [B*64] f32
  float* ws_ia = ws + (size_t)BB * 64;             // [B*64] f32
  float* ws_base = ws + (size_t)2 * BB * 64;       // [B*64] f32
  float* ws_flat = ws + (size_t)3 * BB * 64;       // [3B] f32
  short* Wt_hi = (short*)(ws + (size_t)3 * BB * 64 + 3 * BB);   // [64*2048] bf16
  short* Wt_lo = Wt_hi + (size_t)64 * IMGK;                     // [64*2048] bf16
  short* W1t = Wt_lo + (size_t)64 * IMGK;                       // [64*64] bf16
  float* out = (float*)d_out;

  prep_kernel<<<(IMGK * 64 + 64 * 64 + 255) / 256, 256, 0, stream>>>(
      W_image_w, W_att_ingre_w, Wt_hi, Wt_lo, W1t);
  img_gemm_mfma<<<BB / 16, 256, 0, stream>>>(image_input, Wt_hi, Wt_lo,
                                             W_image_b, b_image, ws_img);
  base_kernel<<<BB / 32, 256, 0, stream>>>(user_input, user_emb, ws_img,
                                           W_att_ingre_w, W_att_ingre_b, b_att_ingre,
                                           ws_base);
  ingre_att_mfma<<<BB / 32, 256, 0, stream>>>(ingre_input, ingre_num, ingre_emb,
                                              W1t, v, ws_base, ws_ia);
  com_score_kernel<<<BB / 32, 256, 0, stream>>>(user_input, item_input, user_emb, item_emb,
                                                W_att_com_w, W_att_com_b, b_att_com, v_c,
                                                ws_img, ws_ia, ws_flat);
  head_kernel<<<BB / 32, 256, 0, stream>>>(user_input, item_input, user_emb, item_emb,
                                           W_concat_w, W_concat_b, b_concat, h_w, h_b,
                                           ws_img, ws_ia, ws_flat, out);
}